// Round 10
// baseline (566.955 us; speedup 1.0000x reference)
//
#include <hip/hip_runtime.h>

// Problem constants (from reference)
constexpr int N   = 50000;
constexpr int E   = 800000;
constexpr int FIN = 512;
constexpr int H1v = 256;
constexpr int H2v = 32;
constexpr int Cv  = 16;

constexpr int NBLK = (N + 1023) / 1024;  // 49 scan blocks

typedef __attribute__((ext_vector_type(8))) short short8;            // 8 bf16 (MFMA frag)
typedef __attribute__((ext_vector_type(4))) float f32x4;             // MFMA C/D frag
typedef __attribute__((ext_vector_type(4))) unsigned short us4;      // 4 bf16
typedef __attribute__((ext_vector_type(4))) unsigned int uint4v;

// fp32 -> bf16 round-to-nearest-even, and back
__device__ inline unsigned short f2bf(float f) {
    unsigned u = __float_as_uint(f);
    return (unsigned short)((u + 0x7FFFu + ((u >> 16) & 1u)) >> 16);
}
__device__ inline float bf2f(unsigned short b) { return __uint_as_float(((unsigned)b) << 16); }

// ---------------- init: W1 split + W2 transpose + cnt zeroing (fused) -----------
// Blocks 0..63: W1 -> bf16 hi/lo MFMA B-frag layout.
// Block  64   : W2 [256][32] -> W2t [32][256] (col-major for fused gemm2).
// Blocks 65.. : cnt[0..N] = 0.

__global__ __launch_bounds__(256) void k_init(const float* __restrict__ W1,
                                              const float* __restrict__ W2,
                                              unsigned short* __restrict__ Wf,
                                              float* __restrict__ W2t,
                                              int* __restrict__ cnt) {
    const int b = blockIdx.x;
    if (b < 64) {
        int t = b * 256 + threadIdx.x;  // 0..16383
        int l = t & 63, nt = (t >> 6) & 15, kt = t >> 10;
        int n = nt * 16 + (l & 15);
        int kb = kt * 32 + (l >> 4) * 8;
        short8 h8, l8;
#pragma unroll
        for (int j = 0; j < 8; ++j) {
            float w = W1[(size_t)(kb + j) * H1v + n];
            unsigned short h = f2bf(w);
            h8[j] = (short)h;
            l8[j] = (short)f2bf(w - bf2f(h));
        }
        size_t base = ((size_t)(kt * 16 + nt) * 2) * 512 + (size_t)l * 8;
        *(short8*)(Wf + base) = h8;
        *(short8*)(Wf + base + 512) = l8;
    } else if (b == 64) {
        const int t = threadIdx.x;
        const int col = t & 31, kb = t >> 5;  // kb 0..7
#pragma unroll
        for (int i = 0; i < 32; ++i) {
            int k = i * 8 + kb;
            W2t[col * H1v + k] = W2[k * H2v + col];
        }
    } else {
        int i = (b - 65) * 256 + threadIdx.x;
        if (i <= N) cnt[i] = 0;
    }
}

// ---------------- degree histogram / CSR build ----------------

__global__ __launch_bounds__(256) void k_hist(const int* __restrict__ dst,
                                              int* __restrict__ cnt) {
    int e = blockIdx.x * 256 + threadIdx.x;
    if (e < E) atomicAdd(&cnt[dst[e]], 1);
}

// Phase 1: per-block (1024 elems) sums.
__global__ __launch_bounds__(256) void k_scan_part(const int* __restrict__ cnt,
                                                   int* __restrict__ bsum) {
    __shared__ int red[256];
    const int t = threadIdx.x;
    const int base = blockIdx.x * 1024 + t * 4;
    int s = 0;
#pragma unroll
    for (int i = 0; i < 4; ++i) {
        int idx = base + i;
        if (idx < N) s += cnt[idx];
    }
    red[t] = s;
    __syncthreads();
    for (int off = 128; off > 0; off >>= 1) {
        if (t < off) red[t] += red[t + off];
        __syncthreads();
    }
    if (t == 0) bsum[blockIdx.x] = red[0];
}

// Phase 2 (fused top + final): block offset computed in-block from bsum (one wave),
// then block-local scan -> row_ptr, cursor, dinv. In-place safe vs cnt.
__global__ __launch_bounds__(256) void k_scan_final(const int* __restrict__ cnt,
                                                    const int* __restrict__ bsum,
                                                    int* __restrict__ row_ptr,
                                                    int* __restrict__ cursor,
                                                    float* __restrict__ dinv) {
    __shared__ int sums[256];
    __shared__ int s_bofs, s_tot;
    const int t = threadIdx.x;

    if (t < 64) {  // one wave: prefix-of-my-block + grand total over bsum[49]
        int v = (t < NBLK) ? bsum[t] : 0;
        int pre = (t < (int)blockIdx.x) ? v : 0;
#pragma unroll
        for (int off = 32; off > 0; off >>= 1) {
            pre += __shfl_down(pre, off, 64);
            v   += __shfl_down(v, off, 64);
        }
        if (t == 0) { s_bofs = pre; s_tot = v; }
    }

    const int base = blockIdx.x * 1024 + t * 4;
    int v[4];
    int local = 0;
#pragma unroll
    for (int i = 0; i < 4; ++i) {
        int idx = base + i;
        v[i] = (idx < N) ? cnt[idx] : 0;
        local += v[i];
    }
    sums[t] = local;
    __syncthreads();
    for (int off = 1; off < 256; off <<= 1) {
        int u = (t >= off) ? sums[t - off] : 0;
        __syncthreads();
        sums[t] += u;
        __syncthreads();
    }
    int run = s_bofs + sums[t] - local;  // exclusive thread offset
#pragma unroll
    for (int i = 0; i < 4; ++i) {
        int idx = base + i;
        if (idx < N) {
            row_ptr[idx] = run;
            cursor[idx] = run;
            dinv[idx] = rsqrtf(1.0f + (float)v[i]);  // +1 self-loop
        }
        run += v[i];
    }
    if (blockIdx.x == NBLK - 1 && t == 0) row_ptr[N] = s_tot;  // == E
}

__global__ __launch_bounds__(256) void k_permute(const int* __restrict__ src,
                                                 const int* __restrict__ dst,
                                                 int* __restrict__ cursor,
                                                 int* __restrict__ srcs) {
    int e = blockIdx.x * 256 + threadIdx.x;
    if (e < E) {
        int pos = atomicAdd(&cursor[dst[e]], 1);
        srcs[pos] = src[e];
    }
}

// ---------------- GEMM 1 (MFMA, split-bf16 x3, LDS-free): [N,512]@[512,256] ------
// ROUND-7 KNOWN-GOOD (110 us, 92 VGPR, no spill). Round-8's deeper register
// pipeline spilled (VGPR 128 + scratch) -> 2.4x regression. Do not deepen.

__device__ inline void split_pair(float x0, float x1, unsigned& hp, unsigned& lp) {
    unsigned u0 = __float_as_uint(x0), u1 = __float_as_uint(x1);
    unsigned h0 = u0 & 0xffff0000u, h1 = u1 & 0xffff0000u;
    float l0 = x0 - __uint_as_float(h0);
    float l1 = x1 - __uint_as_float(h1);
    hp = __builtin_amdgcn_perm(u1, u0, 0x07060302u);  // [u0.hi16, u1.hi16]
    lp = __builtin_amdgcn_perm(__float_as_uint(l1), __float_as_uint(l0), 0x07060302u);
}

__device__ inline void split_frag(const float4& a, const float4& b, short8& hi, short8& lo) {
    unsigned h0, h1, h2, h3, l0, l1, l2, l3;
    split_pair(a.x, a.y, h0, l0);
    split_pair(a.z, a.w, h1, l1);
    split_pair(b.x, b.y, h2, l2);
    split_pair(b.z, b.w, h3, l3);
    uint4v h, l;
    h[0] = h0; h[1] = h1; h[2] = h2; h[3] = h3;
    l[0] = l0; l[1] = l1; l[2] = l2; l[3] = l3;
    hi = __builtin_bit_cast(short8, h);
    lo = __builtin_bit_cast(short8, l);
}

__global__ __launch_bounds__(256, 2) void k_gemm1_mfma(const float* __restrict__ X,
                                                       const unsigned short* __restrict__ Wf,
                                                       const float* __restrict__ dinv,
                                                       unsigned short* __restrict__ Hout) {
    const int tid = threadIdx.x;
    const int w = tid >> 6, l = tid & 63;
    const int wr = w >> 1, wc = w & 1;
    const int row0 = blockIdx.x * 128 + wr * 64;
    const int colb = blockIdx.y;
    const int lm = l & 15;
    const int lk = (l >> 4) * 8;

    const float* ap[4];
    bool ok[4];
#pragma unroll
    for (int i = 0; i < 4; ++i) {
        int r = row0 + i * 16 + lm;
        ok[i] = r < N;
        ap[i] = X + (size_t)r * FIN + lk;
    }
    const unsigned short* bp0 = Wf + (size_t)(colb * 8 + wc * 4) * 1024 + (size_t)l * 8;

    f32x4 acc[4][4];
#pragma unroll
    for (int i = 0; i < 4; ++i)
#pragma unroll
        for (int j = 0; j < 4; ++j) acc[i][j] = (f32x4)0.f;

    float4 a0[4], a1[4];
#pragma unroll
    for (int i = 0; i < 4; ++i) {
        a0[i] = ok[i] ? *(const float4*)(ap[i]) : make_float4(0.f, 0.f, 0.f, 0.f);
        a1[i] = ok[i] ? *(const float4*)(ap[i] + 4) : make_float4(0.f, 0.f, 0.f, 0.f);
    }

    for (int ktg = 0; ktg < 16; ++ktg) {
        const unsigned short* bp = bp0 + (size_t)ktg * 16384;
        short8 Bh[4], Bl[4];
#pragma unroll
        for (int j = 0; j < 4; ++j) {
            Bh[j] = *(const short8*)(bp + j * 1024);
            Bl[j] = *(const short8*)(bp + j * 1024 + 512);
        }

        short8 Ah[4], Al[4];
#pragma unroll
        for (int i = 0; i < 4; ++i) split_frag(a0[i], a1[i], Ah[i], Al[i]);

        if (ktg < 15) {
#pragma unroll
            for (int i = 0; i < 4; ++i) {
                const float* p = ap[i] + (ktg + 1) * 32;
                a0[i] = ok[i] ? *(const float4*)(p) : make_float4(0.f, 0.f, 0.f, 0.f);
                a1[i] = ok[i] ? *(const float4*)(p + 4) : make_float4(0.f, 0.f, 0.f, 0.f);
            }
        }

#pragma unroll
        for (int i = 0; i < 4; ++i)
#pragma unroll
            for (int j = 0; j < 4; ++j) {
                acc[i][j] = __builtin_amdgcn_mfma_f32_16x16x32_bf16(Ah[i], Bh[j], acc[i][j], 0, 0, 0);
                acc[i][j] = __builtin_amdgcn_mfma_f32_16x16x32_bf16(Ah[i], Bl[j], acc[i][j], 0, 0, 0);
                acc[i][j] = __builtin_amdgcn_mfma_f32_16x16x32_bf16(Al[i], Bh[j], acc[i][j], 0, 0, 0);
            }
    }

    const int col0 = colb * 128;
#pragma unroll
    for (int i = 0; i < 4; ++i) {
        int rbase = row0 + i * 16 + (l >> 4) * 4;
        float dv[4];
        bool okr[4];
#pragma unroll
        for (int r = 0; r < 4; ++r) {
            int rr = rbase + r;
            okr[r] = rr < N;
            dv[r] = okr[r] ? dinv[rr] : 0.f;
        }
#pragma unroll
        for (int j = 0; j < 4; ++j) {
            int col = col0 + (wc * 4 + j) * 16 + lm;
#pragma unroll
            for (int r = 0; r < 4; ++r)
                if (okr[r]) Hout[(size_t)(rbase + r) * H1v + col] = f2bf(acc[i][j][r] * dv[r]);
        }
    }
}

// ---------------- fused: agg over h1 (D=256) + GEMM2 [256->32] -> h2 bf16 --------
// Block = 4 dst rows (one wave each). Phase 1: wave gathers CSR neighbors of d
// (8 rows in flight), a1 row = relu(dinv*sum + b1) -> LDS (stride 260: rows land
// on distinct banks; phase-2 reads are same-address broadcast within a row).
// Phase 2: 128 threads (row = t>>5, col = t&31) compute (a1 @ W2)[col] from LDS
// with W2t (col-major, sequential float4, L1-broadcast), *dinv, store bf16 h2.
// Kills the a1 buffer (50 MB write + 50 MB read) and the separate gemm2 dispatch.

__global__ __launch_bounds__(256) void k_agg256_gemm2(const unsigned short* __restrict__ h1,
                                                      const int* __restrict__ rp,
                                                      const int* __restrict__ srcs,
                                                      const float* __restrict__ dinv,
                                                      const float* __restrict__ b1,
                                                      const float* __restrict__ W2t,
                                                      unsigned short* __restrict__ h2) {
    __shared__ float als[4][260];  // 260: rows offset by 4 banks, no conflicts
    const int wave = threadIdx.x >> 6;
    const int lane = threadIdx.x & 63;
    const int d = blockIdx.x * 4 + wave;  // N % 4 == 0
    const int beg = rp[d], end = rp[d + 1];
    const int fo = lane * 4;

    us4 sv = *(const us4*)(h1 + (size_t)d * H1v + fo);  // self-loop
    float ax = bf2f(sv.x), ay = bf2f(sv.y), az = bf2f(sv.z), aw = bf2f(sv.w);
    int j = beg;
    for (; j + 7 < end; j += 8) {  // 8 independent gathers in flight
        us4 v[8];
#pragma unroll
        for (int q = 0; q < 8; ++q)
            v[q] = *(const us4*)(h1 + (size_t)srcs[j + q] * H1v + fo);
#pragma unroll
        for (int q = 0; q < 8; ++q) {
            ax += bf2f(v[q].x); ay += bf2f(v[q].y);
            az += bf2f(v[q].z); aw += bf2f(v[q].w);
        }
    }
    for (; j < end; ++j) {
        us4 v = *(const us4*)(h1 + (size_t)srcs[j] * H1v + fo);
        ax += bf2f(v.x); ay += bf2f(v.y); az += bf2f(v.z); aw += bf2f(v.w);
    }
    const float di = dinv[d];
    const float4 b4 = *(const float4*)(b1 + fo);
    als[wave][fo + 0] = fmaxf(fmaf(di, ax, b4.x), 0.f);
    als[wave][fo + 1] = fmaxf(fmaf(di, ay, b4.y), 0.f);
    als[wave][fo + 2] = fmaxf(fmaf(di, az, b4.z), 0.f);
    als[wave][fo + 3] = fmaxf(fmaf(di, aw, b4.w), 0.f);
    __syncthreads();

    if (threadIdx.x < 128) {
        const int row = threadIdx.x >> 5, col = threadIdx.x & 31;
        const float* wcol = W2t + (size_t)col * H1v;
        float sum = 0.f;
#pragma unroll 8
        for (int k = 0; k < H1v; k += 4) {
            float4 wv = *(const float4*)(wcol + k);
            float4 av = *(const float4*)(&als[row][k]);
            sum = fmaf(av.x, wv.x, sum);
            sum = fmaf(av.y, wv.y, sum);
            sum = fmaf(av.z, wv.z, sum);
            sum = fmaf(av.w, wv.w, sum);
        }
        const int gd = blockIdx.x * 4 + row;
        h2[(size_t)gd * H2v + col] = f2bf(sum * dinv[gd]);
    }
}

// ---------------- fused: agg over h2 (D=32) + GEMM3 [32x16] -> h3 bf16 ----------

__global__ __launch_bounds__(256) void k_agg32_gemm3(const unsigned short* __restrict__ h2,
                                                     const int* __restrict__ rp,
                                                     const int* __restrict__ srcs,
                                                     const float* __restrict__ dinv,
                                                     const float* __restrict__ b2,
                                                     const float* __restrict__ W3,
                                                     unsigned short* __restrict__ h3) {
    __shared__ float als[8][33];       // +1 pad: kills 4-way stride-32 conflicts
    __shared__ float W3s[H2v * Cv];    // 512 floats
    const int t = threadIdx.x;
    *(float2*)(&W3s[t * 2]) = *(const float2*)(W3 + t * 2);

    const int sub = t >> 5, f = t & 31;
    const int d = blockIdx.x * 8 + sub;  // N % 8 == 0
    const int beg = rp[d], end = rp[d + 1];
    float acc = bf2f(h2[(size_t)d * H2v + f]);  // self-loop
    int j = beg;
    for (; j + 3 < end; j += 4) {
        float v0 = bf2f(h2[(size_t)srcs[j] * H2v + f]);
        float v1 = bf2f(h2[(size_t)srcs[j + 1] * H2v + f]);
        float v2 = bf2f(h2[(size_t)srcs[j + 2] * H2v + f]);
        float v3 = bf2f(h2[(size_t)srcs[j + 3] * H2v + f]);
        acc += v0 + v1 + v2 + v3;
    }
    for (; j < end; ++j) acc += bf2f(h2[(size_t)srcs[j] * H2v + f]);
    als[sub][f] = fmaxf(fmaf(dinv[d], acc, b2[f]), 0.f);
    __syncthreads();

    if (t < 128) {
        const int row = t >> 4, col = t & 15;
        float sum = 0.f;
#pragma unroll
        for (int k = 0; k < H2v; ++k) sum = fmaf(als[row][k], W3s[k * Cv + col], sum);
        const int gr = blockIdx.x * 8 + row;
        h3[(size_t)gr * Cv + col] = f2bf(sum * dinv[gr]);
    }
}

// ---------------- final aggregation over h3 (D=16) -> out fp32 ----------------

__global__ __launch_bounds__(256) void k_agg16(const unsigned short* __restrict__ h,
                                               const int* __restrict__ rp,
                                               const int* __restrict__ srcs,
                                               const float* __restrict__ dinv,
                                               const float* __restrict__ bias,
                                               float* __restrict__ out) {
    const int sub = threadIdx.x >> 4;
    const int f = threadIdx.x & 15;
    const int d = blockIdx.x * 16 + sub;
    if (d >= N) return;
    const int beg = rp[d], end = rp[d + 1];
    float acc = bf2f(h[(size_t)d * Cv + f]);  // self-loop
    int j = beg;
    for (; j + 3 < end; j += 4) {
        float v0 = bf2f(h[(size_t)srcs[j] * Cv + f]);
        float v1 = bf2f(h[(size_t)srcs[j + 1] * Cv + f]);
        float v2 = bf2f(h[(size_t)srcs[j + 2] * Cv + f]);
        float v3 = bf2f(h[(size_t)srcs[j + 3] * Cv + f]);
        acc += v0 + v1 + v2 + v3;
    }
    for (; j < end; ++j) acc += bf2f(h[(size_t)srcs[j] * Cv + f]);
    out[(size_t)d * Cv + f] = fmaf(dinv[d], acc, bias[f]);
}

// ---------------- launch ----------------

extern "C" void kernel_launch(void* const* d_in, const int* in_sizes, int n_in,
                              void* d_out, int out_size, void* d_ws, size_t ws_size,
                              hipStream_t stream) {
    const float* x  = (const float*)d_in[0];
    const int*   ei = (const int*)d_in[1];
    const float* W1 = (const float*)d_in[2];
    const float* b1 = (const float*)d_in[3];
    const float* W2 = (const float*)d_in[4];
    const float* b2 = (const float*)d_in[5];
    const float* W3 = (const float*)d_in[6];
    const float* b3 = (const float*)d_in[7];
    const int* src = ei;       // edge_index[0]
    const int* dst = ei + E;   // edge_index[1]
    float* out = (float*)d_out;

    // Workspace layout (bytes):
    // [0       ] dinv    float[50000]
    // [0x40000 ] cnt/rp  int[50001]   (in-place scan)
    // [0x80000 ] cursor  int[50000]
    // [0xB2000 ] bsum    int[49]
    // [0xC0000 ] srcs    int[800000]
    // [0x400000] Wsplit  ushort[262144]  (512 KB)
    // [0x480000] W2t     float[8192]     (32 KB, col-major W2)
    // [5 MiB   ] h1 bf16 [N*256], h2 bf16 [N*32], h3 bf16 [N*16]
    char* ws = (char*)d_ws;
    float* dinv   = (float*)ws;
    int*   cnt    = (int*)(ws + 0x40000);
    int*   rp     = cnt;
    int*   cursor = (int*)(ws + 0x80000);
    int*   bsum   = (int*)(ws + 0xB2000);
    int*   srcs   = (int*)(ws + 0xC0000);
    unsigned short* wsplit = (unsigned short*)(ws + 0x400000);
    float* w2t    = (float*)(ws + 0x480000);
    char* p = ws + (size_t)5 * 1024 * 1024;
    unsigned short* h1 = (unsigned short*)p; p += (size_t)N * H1v * sizeof(unsigned short);
    unsigned short* h2 = (unsigned short*)p; p += (size_t)N * H2v * sizeof(unsigned short);
    unsigned short* h3 = (unsigned short*)p;

    // CSR build + weight prep: 5 dispatches
    k_init<<<65 + (N + 256) / 256, 256, 0, stream>>>(W1, W2, wsplit, w2t, cnt);
    k_hist<<<(E + 255) / 256, 256, 0, stream>>>(dst, cnt);
    k_scan_part<<<NBLK, 256, 0, stream>>>(cnt, bsum);
    k_scan_final<<<NBLK, 256, 0, stream>>>(cnt, bsum, rp, cursor, dinv);
    k_permute<<<(E + 255) / 256, 256, 0, stream>>>(src, dst, cursor, srcs);

    // ---- layer 1: 512 -> 256 (MFMA, LDS-free), ReLU ----
    dim3 g1((N + 127) / 128, 2);
    k_gemm1_mfma<<<g1, 256, 0, stream>>>(x, wsplit, dinv, h1);

    // ---- fused: agg(h1) + GEMM2 -> h2 ----
    k_agg256_gemm2<<<N / 4, 256, 0, stream>>>(h1, rp, srcs, dinv, b1, w2t, h2);

    // ---- fused: agg(h2) + GEMM3 -> h3 ----
    k_agg32_gemm3<<<N / 8, 256, 0, stream>>>(h2, rp, srcs, dinv, b2, W3, h3);

    // ---- final aggregation -> out ----
    k_agg16<<<(N + 15) / 16, 256, 0, stream>>>(h3, rp, srcs, dinv, b3, out);
}